// Round 1
// baseline (207.045 us; speedup 1.0000x reference)
//
#include <hip/hip_runtime.h>
#include <hip/hip_bf16.h>
#include <math.h>

// Problem constants
#define S_LEN   2048
#define BATCH   2
#define DMODEL  1024
#define NHEADS  16
#define DKH     64
#define MROWS   (BATCH * S_LEN)   // 4096

typedef __attribute__((ext_vector_type(8))) __bf16 bf16x8;
typedef __attribute__((ext_vector_type(4))) float f32x4;
typedef __attribute__((ext_vector_type(8))) unsigned short u16x8;

__device__ __forceinline__ float bfu2f(unsigned short u) {
    union { unsigned int i; float f; } v;
    v.i = ((unsigned int)u) << 16;
    return v.f;
}

__device__ __forceinline__ unsigned short f2bfu(float f) {
    union { __bf16 h; unsigned short u; } v;
    v.h = (__bf16)f;    // native RNE cvt
    return v.u;
}

#define LGKM0() __builtin_amdgcn_s_waitcnt(0xc07f)   // lgkmcnt(0), vmcnt free

// global -> LDS direct DMA, 16B per lane. LDS dest must be linear in lane
// order: we pass base + lane*16 exactly (HW uses wave-uniform base + lane*16).
__device__ __forceinline__ void gload_lds16(const void* g, void* l) {
    __builtin_amdgcn_global_load_lds(
        (const __attribute__((address_space(1))) void*)g,
        (__attribute__((address_space(3))) void*)l, 16, 0, 0);
}

// ---------------------------------------------------------------------------
// R14 pre-convert: Wq/Wk/Wv fp32 -> bf16 into ws[24MB..30MB) AND x fp32 ->
// bf16 into d_out scratch (dead until gemm_wo overwrites it at the end).
// With both GEMM operands bf16, gemm_qkv staging becomes pure global_load_lds
// DMA (the m93->m97 +69% lever from the measured ladder).
// ---------------------------------------------------------------------------
__global__ __launch_bounds__(256) void cvt_all(
    const float* __restrict__ W0, const float* __restrict__ W1, const float* __restrict__ W2,
    const float* __restrict__ X,
    unsigned short* __restrict__ Wb,    // [3][1024*1024] bf16
    unsigned short* __restrict__ Xb)    // [4096*1024] bf16 (lives in d_out)
{
    const int y = blockIdx.y;
    const float* src;
    unsigned short* dst;
    if (y < 3) {
        src = (y == 0) ? W0 : (y == 1) ? W1 : W2;
        dst = Wb + (size_t)y * (DMODEL * DMODEL);
    } else {
        src = X + (size_t)(y - 3) * (DMODEL * DMODEL);
        dst = Xb + (size_t)(y - 3) * (DMODEL * DMODEL);
    }
    size_t idx = ((size_t)blockIdx.x * 256 + threadIdx.x) * 8;
    float4 a = *(const float4*)(src + idx);
    float4 b = *(const float4*)(src + idx + 4);
    u16x8 h;
    h[0] = f2bfu(a.x); h[1] = f2bfu(a.y); h[2] = f2bfu(a.z); h[3] = f2bfu(a.w);
    h[4] = f2bfu(b.x); h[5] = f2bfu(b.y); h[6] = f2bfu(b.z); h[7] = f2bfu(b.w);
    *(u16x8*)(dst + idx) = h;
}

// Wo fp32 -> bf16 into the Q region (dead after attn_mfma; runs between
// attn and gemm_wo in stream order).
__global__ __launch_bounds__(256) void cvt_wo(
    const float* __restrict__ W, unsigned short* __restrict__ Wob)
{
    size_t idx = ((size_t)blockIdx.x * 256 + threadIdx.x) * 8;
    float4 a = *(const float4*)(W + idx);
    float4 b = *(const float4*)(W + idx + 4);
    u16x8 h;
    h[0] = f2bfu(a.x); h[1] = f2bfu(a.y); h[2] = f2bfu(a.z); h[3] = f2bfu(a.w);
    h[4] = f2bfu(b.x); h[5] = f2bfu(b.y); h[6] = f2bfu(b.z); h[7] = f2bfu(b.w);
    *(u16x8*)(Wob + idx) = h;
}

// ---------------------------------------------------------------------------
// QKV MFMA GEMM R14: R13 structure (128x128, BK=32, 2-barrier) with staging
// replaced by global_load_lds width-16 DMA for BOTH operands (both now bf16).
// LDS is linear [128][32] halves (64B rows) as global_load_lds requires
// (wave-uniform base + lane*16; no padding allowed -- m104/m173).
// Epilogues (RoPE Q/K, V-transpose) unchanged from measured-best R13.
// ---------------------------------------------------------------------------
__global__ __launch_bounds__(256) void gemm_qkv(
    const unsigned short* __restrict__ Xb,   // bf16 [4096][1024]
    const unsigned short* __restrict__ Wb,   // [3][1024][1024] bf16
    unsigned short* __restrict__ Yq, unsigned short* __restrict__ Yk, unsigned short* __restrict__ Yv)
{
    __shared__ __align__(16) unsigned char pool[36864];
    unsigned short* As = (unsigned short*)pool;        // 128 x 32 linear
    unsigned short* Bs = As + 128 * 32;                // 128 x 32 linear

    const int tid  = threadIdx.x;
    const int wave = tid >> 6;
    const int lane = tid & 63;
    const int c    = lane & 15;
    const int quad = lane >> 4;

    const int m0 = blockIdx.y * 128;
    const int n0 = blockIdx.x * 128;
    const int w_idx = n0 >> 10;
    const int e0    = n0 & 1023;
    const unsigned short* Wsrc = Wb + (size_t)w_idx * (DMODEL * DMODEL);

    const int mhalf = (wave & 1) * 64;
    const int nhalf = (wave >> 1) * 64;

    f32x4 acc[4][4];
#pragma unroll
    for (int i = 0; i < 4; i++)
#pragma unroll
        for (int j = 0; j < 4; j++) acc[i][j] = (f32x4){0.f, 0.f, 0.f, 0.f};

    // DMA staging addressing: wave w covers rows [32w, 32w+32), 16 rows per
    // instruction (64 lanes x 16B = 16 rows x 64B). lane i -> row +i/4,
    // halves (i&3)*8. LDS dest linear => dest byte = inst_base + lane*16.
    const int srow = wave * 32 + (lane >> 2);
    const int scol = (lane & 3) * 8;
    const unsigned short* Asrc = Xb   + (size_t)(m0 + srow) * DMODEL + scol;
    const unsigned short* Bsrc = Wsrc + (size_t)(e0 + srow) * DMODEL + scol;
    unsigned short* Adst = As + srow * 32 + scol;
    unsigned short* Bdst = Bs + srow * 32 + scol;

    for (int k0 = 0; k0 < DMODEL; k0 += 32) {
        __syncthreads();
#pragma unroll
        for (int j = 0; j < 2; j++) {
            gload_lds16(Asrc + (size_t)(j * 16) * DMODEL + k0, Adst + j * 16 * 32);
            gload_lds16(Bsrc + (size_t)(j * 16) * DMODEL + k0, Bdst + j * 16 * 32);
        }
        __syncthreads();   // compiler drains vmcnt(0) here -- data ready

        bf16x8 af[4], bfr[4];
#pragma unroll
        for (int mt = 0; mt < 4; mt++)
            af[mt] = *(const bf16x8*)(&As[(mhalf + mt * 16 + c) * 32 + quad * 8]);
#pragma unroll
        for (int nt = 0; nt < 4; nt++)
            bfr[nt] = *(const bf16x8*)(&Bs[(nhalf + nt * 16 + c) * 32 + quad * 8]);
#pragma unroll
        for (int mt = 0; mt < 4; mt++)
#pragma unroll
            for (int nt = 0; nt < 4; nt++)
                acc[mt][nt] = __builtin_amdgcn_mfma_f32_16x16x32_bf16(af[mt], bfr[nt], acc[mt][nt], 0, 0, 0);
    }

    __syncthreads();   // staging dead; pool becomes epilogue space

    const int h = (e0 + nhalf) >> 6;
    if (w_idx < 2) {
        // Q/K: fp32 slab -> LDS -> row-major readback + in-lane RoPE
        unsigned short* Yqk = (w_idx == 0) ? Yq : Yk;
        float* EPf = (float*)pool + wave * 16 * 68;
        const int row = lane >> 2;
        const int cg  = lane & 3;
#pragma unroll
        for (int mt = 0; mt < 4; mt++) {
            LGKM0();
#pragma unroll
            for (int nt = 0; nt < 4; nt++)
#pragma unroll
                for (int r = 0; r < 4; r++)
                    EPf[(quad * 4 + r) * 68 + nt * 16 + c] = acc[mt][nt][r];
            LGKM0();
            float fl[16];
#pragma unroll
            for (int j = 0; j < 4; j++) {
                float4 v = *(const float4*)(&EPf[row * 68 + cg * 16 + j * 4]);
                fl[j * 4 + 0] = v.x; fl[j * 4 + 1] = v.y;
                fl[j * 4 + 2] = v.z; fl[j * 4 + 3] = v.w;
            }
            int m = m0 + mhalf + mt * 16 + row;
            int s = m & (S_LEN - 1);
            int b = m >> 11;
            u16x8 o0, o1;
#pragma unroll
            for (int pi = 0; pi < 8; pi++) {
                int p = cg * 8 + pi;
                float freq  = exp2f(-(float)p * 0.41524101186092034f);
                float angle = (float)s * freq;
                float sn, cs;
                __sincosf(angle, &sn, &cs);
                float ev = fl[2 * pi], ov = fl[2 * pi + 1];
                float re = ev * cs - ov * sn;
                float ro = ev * sn + ov * cs;
                if (pi < 4) { o0[2 * pi] = f2bfu(re); o0[2 * pi + 1] = f2bfu(ro); }
                else        { o1[2 * (pi - 4)] = f2bfu(re); o1[2 * (pi - 4) + 1] = f2bfu(ro); }
            }
            unsigned short* dst = Yqk + (((size_t)(b * NHEADS + h)) * S_LEN + s) * DKH + cg * 16;
            *(u16x8*)(dst)     = o0;
            *(u16x8*)(dst + 8) = o1;
        }
    } else {
        // V: bf16 transposed tile in LDS; lane = dk writes full 128B lines
        unsigned short* EPb = (unsigned short*)pool + wave * 64 * 72;
        LGKM0();
#pragma unroll
        for (int nt = 0; nt < 4; nt++)
#pragma unroll
            for (int mt = 0; mt < 4; mt++)
#pragma unroll
                for (int r = 0; r < 4; r++)
                    EPb[(nt * 16 + c) * 72 + mt * 16 + quad * 4 + r] = f2bfu(acc[mt][nt][r]);
        LGKM0();
        int mbase = m0 + mhalf;
        int s0 = mbase & (S_LEN - 1);
        int b  = mbase >> 11;
        unsigned short* dst = Yv + (((size_t)(b * NHEADS + h)) * DKH + lane) * S_LEN + s0;
#pragma unroll
        for (int j = 0; j < 8; j++)
            *(u16x8*)(dst + j * 8) = *(const u16x8*)(&EPb[lane * 72 + j * 8]);
    }
}

// ---------------------------------------------------------------------------
// Wo MFMA GEMM R14: 64x128 tile (512 blocks, 2/CU) kept, but BK=32 with
// global_load_lds DMA staging for BOTH operands (A = attn out bf16,
// B = pre-converted Wo bf16). In-loop cvt VALU work eliminated.
// ---------------------------------------------------------------------------
__global__ __launch_bounds__(256) void gemm_wo(
    const unsigned short* __restrict__ X,    // bf16 A, (MROWS x DMODEL)
    const unsigned short* __restrict__ Wob,  // bf16 Wo (1024 x 1024)
    float* __restrict__ Yf)                  // fp32 out
{
    __shared__ __align__(16) unsigned char pool[18432];
    unsigned short* As = (unsigned short*)pool;        // 64 x 32 linear
    unsigned short* Bs = As + 64 * 32;                 // 128 x 32 linear

    const int tid  = threadIdx.x;
    const int wave = tid >> 6;
    const int lane = tid & 63;
    const int c    = lane & 15;
    const int quad = lane >> 4;

    const int m0 = blockIdx.y * 64;
    const int n0 = blockIdx.x * 128;

    const int mhalf = (wave & 1) * 32;
    const int nhalf = (wave >> 1) * 64;

    f32x4 acc[2][4];
#pragma unroll
    for (int i = 0; i < 2; i++)
#pragma unroll
        for (int j = 0; j < 4; j++) acc[i][j] = (f32x4){0.f, 0.f, 0.f, 0.f};

    // A: 64 rows -> 1 DMA inst/wave (rows 16w..16w+16)
    // B: 128 rows -> 2 DMA insts/wave (rows 32w + 16j + lane/4)
    const int arow = wave * 16 + (lane >> 2);
    const int brow = wave * 32 + (lane >> 2);
    const int scol = (lane & 3) * 8;
    const unsigned short* Asrc = X   + (size_t)(m0 + arow) * DMODEL + scol;
    const unsigned short* Bsrc = Wob + (size_t)(n0 + brow) * DMODEL + scol;
    unsigned short* Adst = As + arow * 32 + scol;
    unsigned short* Bdst = Bs + brow * 32 + scol;

    for (int k0 = 0; k0 < DMODEL; k0 += 32) {
        __syncthreads();
        gload_lds16(Asrc + k0, Adst);
#pragma unroll
        for (int j = 0; j < 2; j++)
            gload_lds16(Bsrc + (size_t)(j * 16) * DMODEL + k0, Bdst + j * 16 * 32);
        __syncthreads();

        bf16x8 af[2], bfr[4];
#pragma unroll
        for (int mt = 0; mt < 2; mt++)
            af[mt] = *(const bf16x8*)(&As[(mhalf + mt * 16 + c) * 32 + quad * 8]);
#pragma unroll
        for (int nt = 0; nt < 4; nt++)
            bfr[nt] = *(const bf16x8*)(&Bs[(nhalf + nt * 16 + c) * 32 + quad * 8]);
#pragma unroll
        for (int mt = 0; mt < 2; mt++)
#pragma unroll
            for (int nt = 0; nt < 4; nt++)
                acc[mt][nt] = __builtin_amdgcn_mfma_f32_16x16x32_bf16(af[mt], bfr[nt], acc[mt][nt], 0, 0, 0);
    }

    __syncthreads();

    float* EPf = (float*)pool + wave * 16 * 68;
    const int row = lane >> 2;
    const int cg  = lane & 3;
#pragma unroll
    for (int mt = 0; mt < 2; mt++) {
        LGKM0();
#pragma unroll
        for (int nt = 0; nt < 4; nt++)
#pragma unroll
            for (int r = 0; r < 4; r++)
                EPf[(quad * 4 + r) * 68 + nt * 16 + c] = acc[mt][nt][r];
        LGKM0();
        int m = m0 + mhalf + mt * 16 + row;
        float* dst = Yf + (size_t)m * DMODEL + n0 + nhalf + cg * 16;
#pragma unroll
        for (int j = 0; j < 4; j++)
            *(float4*)(dst + j * 4) = *(const float4*)(&EPf[row * 68 + cg * 16 + j * 4]);
    }
}

// ---------------------------------------------------------------------------
// MFMA flash attention — exact R9/R10 BK=32 version (measured best ~53us).
// Causal, no-max softmax, LPT dispatch, block-shared K/V LDS tiles with reg
// prefetch, mask-free fast path. Unchanged this round.
// ---------------------------------------------------------------------------
__global__ __launch_bounds__(256, 4) void attn_mfma(
    const unsigned short* __restrict__ Q,
    const unsigned short* __restrict__ K,
    const unsigned short* __restrict__ Vt,
    unsigned short* __restrict__ A)
{
    __shared__ unsigned short Ks[32 * 72];
    __shared__ unsigned short Vs[64 * 40];
    __shared__ unsigned short Plds[4][16 * 40];

    const int tid  = threadIdx.x;
    const int wave = tid >> 6;
    const int lane = tid & 63;
    const int c    = lane & 15;
    const int quad = lane >> 4;

    const int bh = blockIdx.x;
    const int b  = bh >> 4;
    const int h  = bh & 15;
    const int qb = (int)(gridDim.y - 1) - (int)blockIdx.y;
    const int q0b = qb * 64;
    const int q0 = q0b + wave * 16;

    const unsigned short* Qb = Q  + (size_t)bh * S_LEN * DKH;
    const unsigned short* Kb = K  + (size_t)bh * S_LEN * DKH;
    const unsigned short* Vb = Vt + (size_t)bh * DKH * S_LEN;

    bf16x8 qf0 = *(const bf16x8*)(Qb + (q0 + c) * DKH + quad * 8);
    bf16x8 qf1 = *(const bf16x8*)(Qb + (q0 + c) * DKH + 32 + quad * 8);

    f32x4 o0 = {0.f,0.f,0.f,0.f}, o1 = o0, o2 = o0, o3 = o0;
    float l[4] = {0.f, 0.f, 0.f, 0.f};

    unsigned short* Pw = &Plds[wave][0];

    const int my_nkb   = (q0 + 16 + 31) >> 5;
    const int nkb_blk  = (q0b + 64 + 31) >> 5;
    const int kb_full  = (q0 >= 31) ? (((q0 - 31) >> 5) + 1) : 0;

    const int krow  = tid >> 3;
    const int kcol8 = (tid & 7) * 8;
    const int vrow  = tid >> 2;
    const int vcol8 = (tid & 3) * 8;

    uint4 gK = *(const uint4*)(Kb + (size_t)krow * DKH + kcol8);
    uint4 gV = *(const uint4*)(Vb + (size_t)vrow * S_LEN + vcol8);

    for (int kb = 0; kb < nkb_blk; kb++) {
        const int k0 = kb * 32;
        __syncthreads();
        *(uint4*)(&Ks[krow * 72 + kcol8]) = gK;
        *(uint4*)(&Vs[vrow * 40 + vcol8]) = gV;
        __syncthreads();
        if (kb + 1 < nkb_blk) {
            gK = *(const uint4*)(Kb + (size_t)(k0 + 32 + krow) * DKH + kcol8);
            gV = *(const uint4*)(Vb + (size_t)vrow * S_LEN + k0 + 32 + vcol8);
        }
        if (kb < my_nkb) {
            bf16x8 k00 = *(const bf16x8*)(&Ks[c * 72 + quad * 8]);
            bf16x8 k01 = *(const bf16x8*)(&Ks[c * 72 + 32 + quad * 8]);
            bf16x8 k10 = *(const bf16x8*)(&Ks[(16 + c) * 72 + quad * 8]);
            bf16x8 k11 = *(const bf16x8*)(&Ks[(16 + c) * 72 + 32 + quad * 8]);
            f32x4 s0 = {0.f,0.f,0.f,0.f}, s1 = {0.f,0.f,0.f,0.f};
            s0 = __builtin_amdgcn_mfma_f32_16x16x32_bf16(qf0, k00, s0, 0, 0, 0);
            s0 = __builtin_amdgcn_mfma_f32_16x16x32_bf16(qf1, k01, s0, 0, 0, 0);
            s1 = __builtin_amdgcn_mfma_f32_16x16x32_bf16(qf0, k10, s1, 0, 0, 0);
            s1 = __builtin_amdgcn_mfma_f32_16x16x32_bf16(qf1, k11, s1, 0, 0, 0);

            if (kb < kb_full) {
#pragma unroll
                for (int r = 0; r < 4; r++) {
                    float e0 = __expf(s0[r] * 0.125f);
                    float e1 = __expf(s1[r] * 0.125f);
                    unsigned short pb0 = f2bfu(e0);
                    unsigned short pb1 = f2bfu(e1);
                    Pw[(quad * 4 + r) * 40 + c]      = pb0;
                    Pw[(quad * 4 + r) * 40 + 16 + c] = pb1;
                    l[r] += bfu2f(pb0) + bfu2f(pb1);
                }
            } else {
#pragma unroll
                for (int r = 0; r < 4; r++) {
                    int qrow = q0 + quad * 4 + r;
                    float e0 = (k0 + c      <= qrow) ? __expf(s0[r] * 0.125f) : 0.0f;
                    float e1 = (k0 + 16 + c <= qrow) ? __expf(s1[r] * 0.125f) : 0.0f;
                    unsigned short pb0 = f2bfu(e0);
                    unsigned short pb1 = f2bfu(e1);
                    Pw[(quad * 4 + r) * 40 + c]      = pb0;
                    Pw[(quad * 4 + r) * 40 + 16 + c] = pb1;
                    l[r] += bfu2f(pb0) + bfu2f(pb1);
                }
            }
            LGKM0();

            bf16x8 pf = *(const bf16x8*)(Pw + c * 40 + quad * 8);

            bf16x8 vf0 = *(const bf16x8*)(&Vs[(0 * 16 + c) * 40 + quad * 8]);
            bf16x8 vf1 = *(const bf16x8*)(&Vs[(1 * 16 + c) * 40 + quad * 8]);
            bf16x8 vf2 = *(const bf16x8*)(&Vs[(2 * 16 + c) * 40 + quad * 8]);
            bf16x8 vf3 = *(const bf16x8*)(&Vs[(3 * 16 + c) * 40 + quad * 8]);
            o0 = __builtin_amdgcn_mfma_f32_16x16x32_bf16(pf, vf0, o0, 0, 0, 0);
            o1 = __builtin_amdgcn_mfma_f32_16x16x32_bf16(pf, vf1, o1, 0, 0, 0);
            o2 = __builtin_amdgcn_mfma_f32_16x16x32_bf16(pf, vf2, o2, 0, 0, 0);
            o3 = __builtin_amdgcn_mfma_f32_16x16x32_bf16(pf, vf3, o3, 0, 0, 0);
        }
    }

#pragma unroll
    for (int m = 1; m < 16; m <<= 1) {
#pragma unroll
        for (int r = 0; r < 4; r++) l[r] += __shfl_xor(l[r], m, 64);
    }

#pragma unroll
    for (int r = 0; r < 4; r++) {
        float inv = 1.0f / l[r];
        int s = q0 + quad * 4 + r;
        unsigned short* Ap = A + ((size_t)b * S_LEN + s) * DMODEL + h * DKH;
        Ap[0 * 16 + c] = f2bfu(o0[r] * inv);
        Ap[1 * 16 + c] = f2bfu(o1[r] * inv);
        Ap[2 * 16 + c] = f2bfu(o2[r] * inv);
        Ap[3 * 16 + c] = f2bfu(o3[r] * inv);
    }
}

extern "C" void kernel_launch(void* const* d_in, const int* in_sizes, int n_in,
                              void* d_out, int out_size, void* d_ws, size_t ws_size,
                              hipStream_t stream) {
    const float* x  = (const float*)d_in[0];
    const float* Wq = (const float*)d_in[1];
    const float* Wk = (const float*)d_in[2];
    const float* Wv = (const float*)d_in[3];
    const float* Wo = (const float*)d_in[4];
    float* out = (float*)d_out;

    // Workspace (exactly 32 MiB -- proven safe):
    //  [0,8)   phase A: Q bf16 [b,h,s,dk];  phase C: Wob bf16 (cvt_wo -> gemm_wo)
    //  [8,16)  K bf16 [b,h,s,dk]
    //  [16,24) V^T bf16 [b,h,dk,s]
    //  [24,32) phase A: Wqkv bf16 (cvt_all -> gemm_qkv); phase B: A (attn -> gemm_wo)
    // d_out (16 MB fp32) doubles as scratch: first 8 MB holds Xb bf16 until
    // gemm_qkv completes; gemm_wo overwrites d_out with the final result.
    unsigned short* Qw = (unsigned short*)d_ws;
    unsigned short* Kw = Qw + (size_t)MROWS * DMODEL;
    unsigned short* Vw = Kw + (size_t)MROWS * DMODEL;
    unsigned short* Wb = Vw + (size_t)MROWS * DMODEL;
    unsigned short* Aw = Wb;    // aliased; QKV completes before attn writes A
    unsigned short* Wob = Qw;   // aliased; Q dead after attn_mfma
    unsigned short* Xb = (unsigned short*)d_out;   // scratch in output buffer

    // y = 0..2: Wq/Wk/Wv (1M floats each); y = 3..6: x quarters (4M floats)
    cvt_all<<<dim3(DMODEL * DMODEL / (256 * 8), 7), 256, 0, stream>>>(Wq, Wk, Wv, x, Wb, Xb);

    gemm_qkv<<<dim3(3 * DMODEL / 128, MROWS / 128), 256, 0, stream>>>(
        Xb, Wb, Qw, Kw, Vw);

    attn_mfma<<<dim3(NHEADS * BATCH, S_LEN / 64), 256, 0, stream>>>(Qw, Kw, Vw, Aw);

    cvt_wo<<<dim3(DMODEL * DMODEL / (256 * 8)), 256, 0, stream>>>(Wo, Wob);

    gemm_wo<<<dim3(DMODEL / 128, MROWS / 64), 256, 0, stream>>>(Aw, Wob, out);
}

// Round 2
// 195.385 us; speedup vs baseline: 1.0597x; 1.0597x over previous
//
#include <hip/hip_runtime.h>
#include <hip/hip_bf16.h>
#include <math.h>

// Problem constants
#define S_LEN   2048
#define BATCH   2
#define DMODEL  1024
#define NHEADS  16
#define DKH     64
#define MROWS   (BATCH * S_LEN)   // 4096

typedef __attribute__((ext_vector_type(8))) __bf16 bf16x8;
typedef __attribute__((ext_vector_type(4))) float f32x4;
typedef __attribute__((ext_vector_type(8))) unsigned short u16x8;

__device__ __forceinline__ float bfu2f(unsigned short u) {
    union { unsigned int i; float f; } v;
    v.i = ((unsigned int)u) << 16;
    return v.f;
}

__device__ __forceinline__ unsigned short f2bfu(float f) {
    union { __bf16 h; unsigned short u; } v;
    v.h = (__bf16)f;    // native RNE cvt
    return v.u;
}

#define LGKM0() __builtin_amdgcn_s_waitcnt(0xc07f)   // lgkmcnt(0), vmcnt free

// global -> LDS direct DMA, 16B per lane. LDS dest must be linear in lane
// order: we pass base + lane*16 exactly (HW uses wave-uniform base + lane*16).
__device__ __forceinline__ void gload_lds16(const void* g, void* l) {
    __builtin_amdgcn_global_load_lds(
        (const __attribute__((address_space(1))) void*)g,
        (__attribute__((address_space(3))) void*)l, 16, 0, 0);
}

// ---------------------------------------------------------------------------
// Pre-convert: Wq/Wk/Wv fp32 -> bf16 into ws[24MB..30MB) AND x fp32 -> bf16
// into d_out scratch (dead until gemm_wo overwrites it at the end).
// ---------------------------------------------------------------------------
__global__ __launch_bounds__(256) void cvt_all(
    const float* __restrict__ W0, const float* __restrict__ W1, const float* __restrict__ W2,
    const float* __restrict__ X,
    unsigned short* __restrict__ Wb,    // [3][1024*1024] bf16
    unsigned short* __restrict__ Xb)    // [4096*1024] bf16 (lives in d_out)
{
    const int y = blockIdx.y;
    const float* src;
    unsigned short* dst;
    if (y < 3) {
        src = (y == 0) ? W0 : (y == 1) ? W1 : W2;
        dst = Wb + (size_t)y * (DMODEL * DMODEL);
    } else {
        src = X + (size_t)(y - 3) * (DMODEL * DMODEL);
        dst = Xb + (size_t)(y - 3) * (DMODEL * DMODEL);
    }
    size_t idx = ((size_t)blockIdx.x * 256 + threadIdx.x) * 8;
    float4 a = *(const float4*)(src + idx);
    float4 b = *(const float4*)(src + idx + 4);
    u16x8 h;
    h[0] = f2bfu(a.x); h[1] = f2bfu(a.y); h[2] = f2bfu(a.z); h[3] = f2bfu(a.w);
    h[4] = f2bfu(b.x); h[5] = f2bfu(b.y); h[6] = f2bfu(b.z); h[7] = f2bfu(b.w);
    *(u16x8*)(dst + idx) = h;
}

// Wo fp32 -> bf16 into the Q region (dead after attn_mfma).
__global__ __launch_bounds__(256) void cvt_wo(
    const float* __restrict__ W, unsigned short* __restrict__ Wob)
{
    size_t idx = ((size_t)blockIdx.x * 256 + threadIdx.x) * 8;
    float4 a = *(const float4*)(W + idx);
    float4 b = *(const float4*)(W + idx + 4);
    u16x8 h;
    h[0] = f2bfu(a.x); h[1] = f2bfu(a.y); h[2] = f2bfu(a.z); h[3] = f2bfu(a.w);
    h[4] = f2bfu(b.x); h[5] = f2bfu(b.y); h[6] = f2bfu(b.z); h[7] = f2bfu(b.w);
    *(u16x8*)(Wob + idx) = h;
}

// ---------------------------------------------------------------------------
// QKV MFMA GEMM R15: R14's DMA staging + T3 minimum 2-phase double-buffer.
// Per K-step: issue next tile's 4 global_load_lds FIRST, then ds_read+MFMA
// the current tile, then ONE barrier (its vmcnt(0) waits only the residual
// latency not hidden by compute). Buffers fully unrolled (compile-time idx).
// LDS: 2 x (A 8KB + B 8KB) = 32KB staging; epilogue reuses pool (36.9KB).
// Epilogues (RoPE Q/K, V-transpose) unchanged from measured-best R13.
// ---------------------------------------------------------------------------
__global__ __launch_bounds__(256) void gemm_qkv(
    const unsigned short* __restrict__ Xb,   // bf16 [4096][1024]
    const unsigned short* __restrict__ Wb,   // [3][1024][1024] bf16
    unsigned short* __restrict__ Yq, unsigned short* __restrict__ Yk, unsigned short* __restrict__ Yv)
{
    __shared__ __align__(16) unsigned char pool[36864];
    unsigned short* base = (unsigned short*)pool;   // buf b: A at b*8192, B at b*8192+4096

    const int tid  = threadIdx.x;
    const int wave = tid >> 6;
    const int lane = tid & 63;
    const int c    = lane & 15;
    const int quad = lane >> 4;

    const int m0 = blockIdx.y * 128;
    const int n0 = blockIdx.x * 128;
    const int w_idx = n0 >> 10;
    const int e0    = n0 & 1023;
    const unsigned short* Wsrc = Wb + (size_t)w_idx * (DMODEL * DMODEL);

    const int mhalf = (wave & 1) * 64;
    const int nhalf = (wave >> 1) * 64;

    f32x4 acc[4][4];
#pragma unroll
    for (int i = 0; i < 4; i++)
#pragma unroll
        for (int j = 0; j < 4; j++) acc[i][j] = (f32x4){0.f, 0.f, 0.f, 0.f};

    // DMA staging: wave w covers rows [32w, 32w+32), 16 rows per instruction
    // (64 lanes x 16B). Dest is linear [128][32] halves => base + lane*16B.
    const int srow = wave * 32 + (lane >> 2);
    const int scol = (lane & 3) * 8;
    const unsigned short* Asrc = Xb   + (size_t)(m0 + srow) * DMODEL + scol;
    const unsigned short* Bsrc = Wsrc + (size_t)(e0 + srow) * DMODEL + scol;
    const int doff = srow * 32 + scol;

#define QKV_STAGE(buf, k0) do {                                                    \
    unsigned short* _A = base + (buf) * 8192;                                      \
    unsigned short* _B = _A + 4096;                                                \
    _Pragma("unroll")                                                              \
    for (int _j = 0; _j < 2; _j++) {                                               \
        gload_lds16(Asrc + (size_t)(_j * 16) * DMODEL + (k0), _A + doff + _j * 512);\
        gload_lds16(Bsrc + (size_t)(_j * 16) * DMODEL + (k0), _B + doff + _j * 512);\
    }                                                                              \
} while (0)

#define QKV_COMPUTE(buf) do {                                                      \
    const unsigned short* _A = base + (buf) * 8192;                                \
    const unsigned short* _B = _A + 4096;                                          \
    bf16x8 af[4], bfr[4];                                                          \
    _Pragma("unroll")                                                              \
    for (int mt = 0; mt < 4; mt++)                                                 \
        af[mt] = *(const bf16x8*)(&_A[(mhalf + mt * 16 + c) * 32 + quad * 8]);     \
    _Pragma("unroll")                                                              \
    for (int nt = 0; nt < 4; nt++)                                                 \
        bfr[nt] = *(const bf16x8*)(&_B[(nhalf + nt * 16 + c) * 32 + quad * 8]);    \
    _Pragma("unroll")                                                              \
    for (int mt = 0; mt < 4; mt++)                                                 \
        _Pragma("unroll")                                                          \
        for (int nt = 0; nt < 4; nt++)                                             \
            acc[mt][nt] = __builtin_amdgcn_mfma_f32_16x16x32_bf16(af[mt], bfr[nt], acc[mt][nt], 0, 0, 0); \
} while (0)

    // 32 K-tiles, double-buffered, one barrier per tile.
    QKV_STAGE(0, 0);
    __syncthreads();                       // drains vmcnt(0): tile 0 ready
    for (int k0 = 0; k0 < DMODEL - 64; k0 += 64) {
        QKV_STAGE(1, k0 + 32);             // issue next loads (latency hides under compute)
        QKV_COMPUTE(0);
        __syncthreads();                   // vmcnt(0)+barrier: tile k0+32 ready
        QKV_STAGE(0, k0 + 64);
        QKV_COMPUTE(1);
        __syncthreads();
    }
    QKV_STAGE(1, DMODEL - 32);
    QKV_COMPUTE(0);
    __syncthreads();
    QKV_COMPUTE(1);

    __syncthreads();   // staging dead; pool becomes epilogue space

    const int h = (e0 + nhalf) >> 6;
    if (w_idx < 2) {
        // Q/K: fp32 slab -> LDS -> row-major readback + in-lane RoPE
        unsigned short* Yqk = (w_idx == 0) ? Yq : Yk;
        float* EPf = (float*)pool + wave * 16 * 68;
        const int row = lane >> 2;
        const int cg  = lane & 3;
#pragma unroll
        for (int mt = 0; mt < 4; mt++) {
            LGKM0();
#pragma unroll
            for (int nt = 0; nt < 4; nt++)
#pragma unroll
                for (int r = 0; r < 4; r++)
                    EPf[(quad * 4 + r) * 68 + nt * 16 + c] = acc[mt][nt][r];
            LGKM0();
            float fl[16];
#pragma unroll
            for (int j = 0; j < 4; j++) {
                float4 v = *(const float4*)(&EPf[row * 68 + cg * 16 + j * 4]);
                fl[j * 4 + 0] = v.x; fl[j * 4 + 1] = v.y;
                fl[j * 4 + 2] = v.z; fl[j * 4 + 3] = v.w;
            }
            int m = m0 + mhalf + mt * 16 + row;
            int s = m & (S_LEN - 1);
            int b = m >> 11;
            u16x8 o0, o1;
#pragma unroll
            for (int pi = 0; pi < 8; pi++) {
                int p = cg * 8 + pi;
                float freq  = exp2f(-(float)p * 0.41524101186092034f);
                float angle = (float)s * freq;
                float sn, cs;
                __sincosf(angle, &sn, &cs);
                float ev = fl[2 * pi], ov = fl[2 * pi + 1];
                float re = ev * cs - ov * sn;
                float ro = ev * sn + ov * cs;
                if (pi < 4) { o0[2 * pi] = f2bfu(re); o0[2 * pi + 1] = f2bfu(ro); }
                else        { o1[2 * (pi - 4)] = f2bfu(re); o1[2 * (pi - 4) + 1] = f2bfu(ro); }
            }
            unsigned short* dst = Yqk + (((size_t)(b * NHEADS + h)) * S_LEN + s) * DKH + cg * 16;
            *(u16x8*)(dst)     = o0;
            *(u16x8*)(dst + 8) = o1;
        }
    } else {
        // V: bf16 transposed tile in LDS; lane = dk writes full 128B lines
        unsigned short* EPb = (unsigned short*)pool + wave * 64 * 72;
        LGKM0();
#pragma unroll
        for (int nt = 0; nt < 4; nt++)
#pragma unroll
            for (int mt = 0; mt < 4; mt++)
#pragma unroll
                for (int r = 0; r < 4; r++)
                    EPb[(nt * 16 + c) * 72 + mt * 16 + quad * 4 + r] = f2bfu(acc[mt][nt][r]);
        LGKM0();
        int mbase = m0 + mhalf;
        int s0 = mbase & (S_LEN - 1);
        int b  = mbase >> 11;
        unsigned short* dst = Yv + (((size_t)(b * NHEADS + h)) * DKH + lane) * S_LEN + s0;
#pragma unroll
        for (int j = 0; j < 8; j++)
            *(u16x8*)(dst + j * 8) = *(const u16x8*)(&EPb[lane * 72 + j * 8]);
    }
#undef QKV_STAGE
#undef QKV_COMPUTE
}

// ---------------------------------------------------------------------------
// Wo MFMA GEMM R15: 64x128 tile, BK=32, DMA staging + same 2-phase dbuf.
// LDS: 2 x (A 4KB + B 8KB) = 24KB; epilogue (17.4KB) reuses pool.
// ---------------------------------------------------------------------------
__global__ __launch_bounds__(256) void gemm_wo(
    const unsigned short* __restrict__ X,    // bf16 A, (MROWS x DMODEL)
    const unsigned short* __restrict__ Wob,  // bf16 Wo (1024 x 1024)
    float* __restrict__ Yf)                  // fp32 out
{
    __shared__ __align__(16) unsigned char pool[24576];
    unsigned short* base = (unsigned short*)pool;   // buf b: A at b*6144, B at b*6144+2048

    const int tid  = threadIdx.x;
    const int wave = tid >> 6;
    const int lane = tid & 63;
    const int c    = lane & 15;
    const int quad = lane >> 4;

    const int m0 = blockIdx.y * 64;
    const int n0 = blockIdx.x * 128;

    const int mhalf = (wave & 1) * 32;
    const int nhalf = (wave >> 1) * 64;

    f32x4 acc[2][4];
#pragma unroll
    for (int i = 0; i < 2; i++)
#pragma unroll
        for (int j = 0; j < 4; j++) acc[i][j] = (f32x4){0.f, 0.f, 0.f, 0.f};

    // A: 64 rows -> 1 DMA inst/wave; B: 128 rows -> 2 DMA insts/wave
    const int arow = wave * 16 + (lane >> 2);
    const int brow = wave * 32 + (lane >> 2);
    const int scol = (lane & 3) * 8;
    const unsigned short* Asrc = X   + (size_t)(m0 + arow) * DMODEL + scol;
    const unsigned short* Bsrc = Wob + (size_t)(n0 + brow) * DMODEL + scol;
    const int adoff = arow * 32 + scol;
    const int bdoff = brow * 32 + scol;

#define WO_STAGE(buf, k0) do {                                                     \
    unsigned short* _A = base + (buf) * 6144;                                      \
    unsigned short* _B = _A + 2048;                                                \
    gload_lds16(Asrc + (k0), _A + adoff);                                          \
    _Pragma("unroll")                                                              \
    for (int _j = 0; _j < 2; _j++)                                                 \
        gload_lds16(Bsrc + (size_t)(_j * 16) * DMODEL + (k0), _B + bdoff + _j * 512);\
} while (0)

#define WO_COMPUTE(buf) do {                                                       \
    const unsigned short* _A = base + (buf) * 6144;                                \
    const unsigned short* _B = _A + 2048;                                          \
    bf16x8 af[2], bfr[4];                                                          \
    _Pragma("unroll")                                                              \
    for (int mt = 0; mt < 2; mt++)                                                 \
        af[mt] = *(const bf16x8*)(&_A[(mhalf + mt * 16 + c) * 32 + quad * 8]);     \
    _Pragma("unroll")                                                              \
    for (int nt = 0; nt < 4; nt++)                                                 \
        bfr[nt] = *(const bf16x8*)(&_B[(nhalf + nt * 16 + c) * 32 + quad * 8]);    \
    _Pragma("unroll")                                                              \
    for (int mt = 0; mt < 2; mt++)                                                 \
        _Pragma("unroll")                                                          \
        for (int nt = 0; nt < 4; nt++)                                             \
            acc[mt][nt] = __builtin_amdgcn_mfma_f32_16x16x32_bf16(af[mt], bfr[nt], acc[mt][nt], 0, 0, 0); \
} while (0)

    WO_STAGE(0, 0);
    __syncthreads();
    for (int k0 = 0; k0 < DMODEL - 64; k0 += 64) {
        WO_STAGE(1, k0 + 32);
        WO_COMPUTE(0);
        __syncthreads();
        WO_STAGE(0, k0 + 64);
        WO_COMPUTE(1);
        __syncthreads();
    }
    WO_STAGE(1, DMODEL - 32);
    WO_COMPUTE(0);
    __syncthreads();
    WO_COMPUTE(1);

    __syncthreads();

    float* EPf = (float*)pool + wave * 16 * 68;
    const int row = lane >> 2;
    const int cg  = lane & 3;
#pragma unroll
    for (int mt = 0; mt < 2; mt++) {
        LGKM0();
#pragma unroll
        for (int nt = 0; nt < 4; nt++)
#pragma unroll
            for (int r = 0; r < 4; r++)
                EPf[(quad * 4 + r) * 68 + nt * 16 + c] = acc[mt][nt][r];
        LGKM0();
        int m = m0 + mhalf + mt * 16 + row;
        float* dst = Yf + (size_t)m * DMODEL + n0 + nhalf + cg * 16;
#pragma unroll
        for (int j = 0; j < 4; j++)
            *(float4*)(dst + j * 4) = *(const float4*)(&EPf[row * 68 + cg * 16 + j * 4]);
    }
#undef WO_STAGE
#undef WO_COMPUTE
}

// ---------------------------------------------------------------------------
// MFMA flash attention — exact R9/R10 BK=32 version (measured best ~53us).
// Unchanged this round.
// ---------------------------------------------------------------------------
__global__ __launch_bounds__(256, 4) void attn_mfma(
    const unsigned short* __restrict__ Q,
    const unsigned short* __restrict__ K,
    const unsigned short* __restrict__ Vt,
    unsigned short* __restrict__ A)
{
    __shared__ unsigned short Ks[32 * 72];
    __shared__ unsigned short Vs[64 * 40];
    __shared__ unsigned short Plds[4][16 * 40];

    const int tid  = threadIdx.x;
    const int wave = tid >> 6;
    const int lane = tid & 63;
    const int c    = lane & 15;
    const int quad = lane >> 4;

    const int bh = blockIdx.x;
    const int b  = bh >> 4;
    const int h  = bh & 15;
    const int qb = (int)(gridDim.y - 1) - (int)blockIdx.y;
    const int q0b = qb * 64;
    const int q0 = q0b + wave * 16;

    const unsigned short* Qb = Q  + (size_t)bh * S_LEN * DKH;
    const unsigned short* Kb = K  + (size_t)bh * S_LEN * DKH;
    const unsigned short* Vb = Vt + (size_t)bh * DKH * S_LEN;

    bf16x8 qf0 = *(const bf16x8*)(Qb + (q0 + c) * DKH + quad * 8);
    bf16x8 qf1 = *(const bf16x8*)(Qb + (q0 + c) * DKH + 32 + quad * 8);

    f32x4 o0 = {0.f,0.f,0.f,0.f}, o1 = o0, o2 = o0, o3 = o0;
    float l[4] = {0.f, 0.f, 0.f, 0.f};

    unsigned short* Pw = &Plds[wave][0];

    const int my_nkb   = (q0 + 16 + 31) >> 5;
    const int nkb_blk  = (q0b + 64 + 31) >> 5;
    const int kb_full  = (q0 >= 31) ? (((q0 - 31) >> 5) + 1) : 0;

    const int krow  = tid >> 3;
    const int kcol8 = (tid & 7) * 8;
    const int vrow  = tid >> 2;
    const int vcol8 = (tid & 3) * 8;

    uint4 gK = *(const uint4*)(Kb + (size_t)krow * DKH + kcol8);
    uint4 gV = *(const uint4*)(Vb + (size_t)vrow * S_LEN + vcol8);

    for (int kb = 0; kb < nkb_blk; kb++) {
        const int k0 = kb * 32;
        __syncthreads();
        *(uint4*)(&Ks[krow * 72 + kcol8]) = gK;
        *(uint4*)(&Vs[vrow * 40 + vcol8]) = gV;
        __syncthreads();
        if (kb + 1 < nkb_blk) {
            gK = *(const uint4*)(Kb + (size_t)(k0 + 32 + krow) * DKH + kcol8);
            gV = *(const uint4*)(Vb + (size_t)vrow * S_LEN + k0 + 32 + vcol8);
        }
        if (kb < my_nkb) {
            bf16x8 k00 = *(const bf16x8*)(&Ks[c * 72 + quad * 8]);
            bf16x8 k01 = *(const bf16x8*)(&Ks[c * 72 + 32 + quad * 8]);
            bf16x8 k10 = *(const bf16x8*)(&Ks[(16 + c) * 72 + quad * 8]);
            bf16x8 k11 = *(const bf16x8*)(&Ks[(16 + c) * 72 + 32 + quad * 8]);
            f32x4 s0 = {0.f,0.f,0.f,0.f}, s1 = {0.f,0.f,0.f,0.f};
            s0 = __builtin_amdgcn_mfma_f32_16x16x32_bf16(qf0, k00, s0, 0, 0, 0);
            s0 = __builtin_amdgcn_mfma_f32_16x16x32_bf16(qf1, k01, s0, 0, 0, 0);
            s1 = __builtin_amdgcn_mfma_f32_16x16x32_bf16(qf0, k10, s1, 0, 0, 0);
            s1 = __builtin_amdgcn_mfma_f32_16x16x32_bf16(qf1, k11, s1, 0, 0, 0);

            if (kb < kb_full) {
#pragma unroll
                for (int r = 0; r < 4; r++) {
                    float e0 = __expf(s0[r] * 0.125f);
                    float e1 = __expf(s1[r] * 0.125f);
                    unsigned short pb0 = f2bfu(e0);
                    unsigned short pb1 = f2bfu(e1);
                    Pw[(quad * 4 + r) * 40 + c]      = pb0;
                    Pw[(quad * 4 + r) * 40 + 16 + c] = pb1;
                    l[r] += bfu2f(pb0) + bfu2f(pb1);
                }
            } else {
#pragma unroll
                for (int r = 0; r < 4; r++) {
                    int qrow = q0 + quad * 4 + r;
                    float e0 = (k0 + c      <= qrow) ? __expf(s0[r] * 0.125f) : 0.0f;
                    float e1 = (k0 + 16 + c <= qrow) ? __expf(s1[r] * 0.125f) : 0.0f;
                    unsigned short pb0 = f2bfu(e0);
                    unsigned short pb1 = f2bfu(e1);
                    Pw[(quad * 4 + r) * 40 + c]      = pb0;
                    Pw[(quad * 4 + r) * 40 + 16 + c] = pb1;
                    l[r] += bfu2f(pb0) + bfu2f(pb1);
                }
            }
            LGKM0();

            bf16x8 pf = *(const bf16x8*)(Pw + c * 40 + quad * 8);

            bf16x8 vf0 = *(const bf16x8*)(&Vs[(0 * 16 + c) * 40 + quad * 8]);
            bf16x8 vf1 = *(const bf16x8*)(&Vs[(1 * 16 + c) * 40 + quad * 8]);
            bf16x8 vf2 = *(const bf16x8*)(&Vs[(2 * 16 + c) * 40 + quad * 8]);
            bf16x8 vf3 = *(const bf16x8*)(&Vs[(3 * 16 + c) * 40 + quad * 8]);
            o0 = __builtin_amdgcn_mfma_f32_16x16x32_bf16(pf, vf0, o0, 0, 0, 0);
            o1 = __builtin_amdgcn_mfma_f32_16x16x32_bf16(pf, vf1, o1, 0, 0, 0);
            o2 = __builtin_amdgcn_mfma_f32_16x16x32_bf16(pf, vf2, o2, 0, 0, 0);
            o3 = __builtin_amdgcn_mfma_f32_16x16x32_bf16(pf, vf3, o3, 0, 0, 0);
        }
    }

#pragma unroll
    for (int m = 1; m < 16; m <<= 1) {
#pragma unroll
        for (int r = 0; r < 4; r++) l[r] += __shfl_xor(l[r], m, 64);
    }

#pragma unroll
    for (int r = 0; r < 4; r++) {
        float inv = 1.0f / l[r];
        int s = q0 + quad * 4 + r;
        unsigned short* Ap = A + ((size_t)b * S_LEN + s) * DMODEL + h * DKH;
        Ap[0 * 16 + c] = f2bfu(o0[r] * inv);
        Ap[1 * 16 + c] = f2bfu(o1[r] * inv);
        Ap[2 * 16 + c] = f2bfu(o2[r] * inv);
        Ap[3 * 16 + c] = f2bfu(o3[r] * inv);
    }
}

extern "C" void kernel_launch(void* const* d_in, const int* in_sizes, int n_in,
                              void* d_out, int out_size, void* d_ws, size_t ws_size,
                              hipStream_t stream) {
    const float* x  = (const float*)d_in[0];
    const float* Wq = (const float*)d_in[1];
    const float* Wk = (const float*)d_in[2];
    const float* Wv = (const float*)d_in[3];
    const float* Wo = (const float*)d_in[4];
    float* out = (float*)d_out;

    // Workspace (exactly 32 MiB):
    //  [0,8)   phase A: Q bf16;  phase C: Wob bf16 (cvt_wo -> gemm_wo)
    //  [8,16)  K bf16
    //  [16,24) V^T bf16
    //  [24,32) phase A: Wqkv bf16; phase B: A (attn -> gemm_wo)
    // d_out doubles as scratch: first 8 MB holds Xb bf16 until gemm_qkv done.
    unsigned short* Qw = (unsigned short*)d_ws;
    unsigned short* Kw = Qw + (size_t)MROWS * DMODEL;
    unsigned short* Vw = Kw + (size_t)MROWS * DMODEL;
    unsigned short* Wb = Vw + (size_t)MROWS * DMODEL;
    unsigned short* Aw = Wb;    // aliased; QKV completes before attn writes A
    unsigned short* Wob = Qw;   // aliased; Q dead after attn_mfma
    unsigned short* Xb = (unsigned short*)d_out;   // scratch in output buffer

    cvt_all<<<dim3(DMODEL * DMODEL / (256 * 8), 7), 256, 0, stream>>>(Wq, Wk, Wv, x, Wb, Xb);

    gemm_qkv<<<dim3(3 * DMODEL / 128, MROWS / 128), 256, 0, stream>>>(
        Xb, Wb, Qw, Kw, Vw);

    attn_mfma<<<dim3(NHEADS * BATCH, S_LEN / 64), 256, 0, stream>>>(Qw, Kw, Vw, Aw);

    cvt_wo<<<dim3(DMODEL * DMODEL / (256 * 8)), 256, 0, stream>>>(Wo, Wob);

    gemm_wo<<<dim3(DMODEL / 128, MROWS / 64), 256, 0, stream>>>(Aw, Wob, out);
}

// Round 3
// 190.708 us; speedup vs baseline: 1.0857x; 1.0245x over previous
//
#include <hip/hip_runtime.h>
#include <hip/hip_bf16.h>
#include <math.h>

// Problem constants
#define S_LEN   2048
#define BATCH   2
#define DMODEL  1024
#define NHEADS  16
#define DKH     64
#define MROWS   (BATCH * S_LEN)   // 4096

typedef __attribute__((ext_vector_type(8))) __bf16 bf16x8;
typedef __attribute__((ext_vector_type(4))) float f32x4;
typedef __attribute__((ext_vector_type(8))) unsigned short u16x8;

__device__ __forceinline__ float bfu2f(unsigned short u) {
    union { unsigned int i; float f; } v;
    v.i = ((unsigned int)u) << 16;
    return v.f;
}

__device__ __forceinline__ unsigned short f2bfu(float f) {
    union { __bf16 h; unsigned short u; } v;
    v.h = (__bf16)f;    // native RNE cvt
    return v.u;
}

#define LGKM0() __builtin_amdgcn_s_waitcnt(0xc07f)   // lgkmcnt(0), vmcnt free

// counted-vmcnt + raw barrier: loads beyond the oldest tile stay IN FLIGHT
// across the barrier (T4). sched_barrier(0) fences compiler hoisting of the
// downstream ds_reads above the barrier (guide rule #18).
#define VMCNT_BAR(n) do {                                        \
    asm volatile("s_waitcnt vmcnt(" #n ")" ::: "memory");        \
    __builtin_amdgcn_s_barrier();                                \
    __builtin_amdgcn_sched_barrier(0);                           \
} while (0)

// global -> LDS direct DMA, 16B per lane (dest = wave-uniform base + lane*16).
__device__ __forceinline__ void gload_lds16(const void* g, void* l) {
    __builtin_amdgcn_global_load_lds(
        (const __attribute__((address_space(1))) void*)g,
        (__attribute__((address_space(3))) void*)l, 16, 0, 0);
}

// ---------------------------------------------------------------------------
// Pre-convert: Wq/Wk/Wv fp32 -> bf16 into ws[24MB..30MB) AND x fp32 -> bf16
// into d_out scratch (dead until gemm_wo overwrites it at the end).
// ---------------------------------------------------------------------------
__global__ __launch_bounds__(256) void cvt_all(
    const float* __restrict__ W0, const float* __restrict__ W1, const float* __restrict__ W2,
    const float* __restrict__ X,
    unsigned short* __restrict__ Wb,    // [3][1024*1024] bf16
    unsigned short* __restrict__ Xb)    // [4096*1024] bf16 (lives in d_out)
{
    const int y = blockIdx.y;
    const float* src;
    unsigned short* dst;
    if (y < 3) {
        src = (y == 0) ? W0 : (y == 1) ? W1 : W2;
        dst = Wb + (size_t)y * (DMODEL * DMODEL);
    } else {
        src = X + (size_t)(y - 3) * (DMODEL * DMODEL);
        dst = Xb + (size_t)(y - 3) * (DMODEL * DMODEL);
    }
    size_t idx = ((size_t)blockIdx.x * 256 + threadIdx.x) * 8;
    float4 a = *(const float4*)(src + idx);
    float4 b = *(const float4*)(src + idx + 4);
    u16x8 h;
    h[0] = f2bfu(a.x); h[1] = f2bfu(a.y); h[2] = f2bfu(a.z); h[3] = f2bfu(a.w);
    h[4] = f2bfu(b.x); h[5] = f2bfu(b.y); h[6] = f2bfu(b.z); h[7] = f2bfu(b.w);
    *(u16x8*)(dst + idx) = h;
}

// Wo fp32 -> bf16 into the Q region (dead after attn_mfma).
__global__ __launch_bounds__(256) void cvt_wo(
    const float* __restrict__ W, unsigned short* __restrict__ Wob)
{
    size_t idx = ((size_t)blockIdx.x * 256 + threadIdx.x) * 8;
    float4 a = *(const float4*)(W + idx);
    float4 b = *(const float4*)(W + idx + 4);
    u16x8 h;
    h[0] = f2bfu(a.x); h[1] = f2bfu(a.y); h[2] = f2bfu(a.z); h[3] = f2bfu(a.w);
    h[4] = f2bfu(b.x); h[5] = f2bfu(b.y); h[6] = f2bfu(b.z); h[7] = f2bfu(b.w);
    *(u16x8*)(Wob + idx) = h;
}

// ---------------------------------------------------------------------------
// QKV MFMA GEMM R16: 3-buffer counted-vmcnt pipeline. Per K-tile u:
//   vmcnt(4)  -> oldest tile (u) landed; tile u+1's 4 loads REMAIN in flight
//   s_barrier -> all waves have tile u; all waves finished compute(u-1)
//   stage tile u+2 into buf[(u+2)%3]  (== buf[(u-1)%3], reads done ^)
//   compute tile u from buf[u%3]
// LDS: 3 x (A 8KB + B 8KB) = 48KB -> 3 blocks/CU (grid is 3/CU exact).
// Epilogues (RoPE Q/K, V-transpose) unchanged.
// ---------------------------------------------------------------------------
__global__ __launch_bounds__(256) void gemm_qkv(
    const unsigned short* __restrict__ Xb,   // bf16 [4096][1024]
    const unsigned short* __restrict__ Wb,   // [3][1024][1024] bf16
    unsigned short* __restrict__ Yq, unsigned short* __restrict__ Yk, unsigned short* __restrict__ Yv)
{
    __shared__ __align__(16) unsigned char pool[49152];
    unsigned short* base = (unsigned short*)pool;   // buf b: A at b*8192, B at b*8192+4096

    const int tid  = threadIdx.x;
    const int wave = tid >> 6;
    const int lane = tid & 63;
    const int c    = lane & 15;
    const int quad = lane >> 4;

    const int m0 = blockIdx.y * 128;
    const int n0 = blockIdx.x * 128;
    const int w_idx = n0 >> 10;
    const int e0    = n0 & 1023;
    const unsigned short* Wsrc = Wb + (size_t)w_idx * (DMODEL * DMODEL);

    const int mhalf = (wave & 1) * 64;
    const int nhalf = (wave >> 1) * 64;

    f32x4 acc[4][4];
#pragma unroll
    for (int i = 0; i < 4; i++)
#pragma unroll
        for (int j = 0; j < 4; j++) acc[i][j] = (f32x4){0.f, 0.f, 0.f, 0.f};

    // DMA staging: wave w covers rows [32w, 32w+32), 16 rows per instruction.
    // dest halves = wave*1024 + lane*8  => base + lane*16B (linear) ✓
    const int srow = wave * 32 + (lane >> 2);
    const int scol = (lane & 3) * 8;
    const unsigned short* Asrc = Xb   + (size_t)(m0 + srow) * DMODEL + scol;
    const unsigned short* Bsrc = Wsrc + (size_t)(e0 + srow) * DMODEL + scol;
    const int doff = srow * 32 + scol;

#define QKV_STAGE(buf, kt) do {                                                    \
    unsigned short* _A = base + (buf) * 8192;                                      \
    unsigned short* _B = _A + 4096;                                                \
    const int _k0 = (kt) * 32;                                                     \
    _Pragma("unroll")                                                              \
    for (int _j = 0; _j < 2; _j++) {                                               \
        gload_lds16(Asrc + (size_t)(_j * 16) * DMODEL + _k0, _A + doff + _j * 512);\
        gload_lds16(Bsrc + (size_t)(_j * 16) * DMODEL + _k0, _B + doff + _j * 512);\
    }                                                                              \
} while (0)

#define QKV_COMPUTE(buf) do {                                                      \
    const unsigned short* _A = base + (buf) * 8192;                                \
    const unsigned short* _B = _A + 4096;                                          \
    bf16x8 af[4], bfr[4];                                                          \
    _Pragma("unroll")                                                              \
    for (int mt = 0; mt < 4; mt++)                                                 \
        af[mt] = *(const bf16x8*)(&_A[(mhalf + mt * 16 + c) * 32 + quad * 8]);     \
    _Pragma("unroll")                                                              \
    for (int nt = 0; nt < 4; nt++)                                                 \
        bfr[nt] = *(const bf16x8*)(&_B[(nhalf + nt * 16 + c) * 32 + quad * 8]);    \
    _Pragma("unroll")                                                              \
    for (int mt = 0; mt < 4; mt++)                                                 \
        _Pragma("unroll")                                                          \
        for (int nt = 0; nt < 4; nt++)                                             \
            acc[mt][nt] = __builtin_amdgcn_mfma_f32_16x16x32_bf16(af[mt], bfr[nt], acc[mt][nt], 0, 0, 0); \
} while (0)

    // 32 K-tiles. Prologue: tiles 0,1 in flight (8 loads).
    QKV_STAGE(0, 0);
    QKV_STAGE(1, 1);
    // Tiles 0..29, buffer indices static via x3 unroll; stage tiles 2..31.
    for (int g = 0; g < 10; ++g) {
        const int t = g * 3;
        VMCNT_BAR(4); QKV_STAGE(2, t + 2); QKV_COMPUTE(0);
        VMCNT_BAR(4); QKV_STAGE(0, t + 3); QKV_COMPUTE(1);
        VMCNT_BAR(4); QKV_STAGE(1, t + 4); QKV_COMPUTE(2);
    }
    // Tail: tile 30 (outstanding 30,31 -> vmcnt(4)), tile 31 (vmcnt(0)).
    VMCNT_BAR(4); QKV_COMPUTE(0);
    VMCNT_BAR(0); QKV_COMPUTE(1);

    __syncthreads();   // staging dead; pool becomes epilogue space

    const int h = (e0 + nhalf) >> 6;
    if (w_idx < 2) {
        // Q/K: fp32 slab -> LDS -> row-major readback + in-lane RoPE
        unsigned short* Yqk = (w_idx == 0) ? Yq : Yk;
        float* EPf = (float*)pool + wave * 16 * 68;
        const int row = lane >> 2;
        const int cg  = lane & 3;
#pragma unroll
        for (int mt = 0; mt < 4; mt++) {
            LGKM0();
#pragma unroll
            for (int nt = 0; nt < 4; nt++)
#pragma unroll
                for (int r = 0; r < 4; r++)
                    EPf[(quad * 4 + r) * 68 + nt * 16 + c] = acc[mt][nt][r];
            LGKM0();
            float fl[16];
#pragma unroll
            for (int j = 0; j < 4; j++) {
                float4 v = *(const float4*)(&EPf[row * 68 + cg * 16 + j * 4]);
                fl[j * 4 + 0] = v.x; fl[j * 4 + 1] = v.y;
                fl[j * 4 + 2] = v.z; fl[j * 4 + 3] = v.w;
            }
            int m = m0 + mhalf + mt * 16 + row;
            int s = m & (S_LEN - 1);
            int b = m >> 11;
            u16x8 o0, o1;
#pragma unroll
            for (int pi = 0; pi < 8; pi++) {
                int p = cg * 8 + pi;
                float freq  = exp2f(-(float)p * 0.41524101186092034f);
                float angle = (float)s * freq;
                float sn, cs;
                __sincosf(angle, &sn, &cs);
                float ev = fl[2 * pi], ov = fl[2 * pi + 1];
                float re = ev * cs - ov * sn;
                float ro = ev * sn + ov * cs;
                if (pi < 4) { o0[2 * pi] = f2bfu(re); o0[2 * pi + 1] = f2bfu(ro); }
                else        { o1[2 * (pi - 4)] = f2bfu(re); o1[2 * (pi - 4) + 1] = f2bfu(ro); }
            }
            unsigned short* dst = Yqk + (((size_t)(b * NHEADS + h)) * S_LEN + s) * DKH + cg * 16;
            *(u16x8*)(dst)     = o0;
            *(u16x8*)(dst + 8) = o1;
        }
    } else {
        // V: bf16 transposed tile in LDS; lane = dk writes full 128B lines
        unsigned short* EPb = (unsigned short*)pool + wave * 64 * 72;
        LGKM0();
#pragma unroll
        for (int nt = 0; nt < 4; nt++)
#pragma unroll
            for (int mt = 0; mt < 4; mt++)
#pragma unroll
                for (int r = 0; r < 4; r++)
                    EPb[(nt * 16 + c) * 72 + mt * 16 + quad * 4 + r] = f2bfu(acc[mt][nt][r]);
        LGKM0();
        int mbase = m0 + mhalf;
        int s0 = mbase & (S_LEN - 1);
        int b  = mbase >> 11;
        unsigned short* dst = Yv + (((size_t)(b * NHEADS + h)) * DKH + lane) * S_LEN + s0;
#pragma unroll
        for (int j = 0; j < 8; j++)
            *(u16x8*)(dst + j * 8) = *(const u16x8*)(&EPb[lane * 72 + j * 8]);
    }
#undef QKV_STAGE
#undef QKV_COMPUTE
}

// ---------------------------------------------------------------------------
// Wo MFMA GEMM R16: same 3-buffer counted-vmcnt pipeline (3 loads/tile ->
// steady-state vmcnt(3)). 64x128 tile, BK=32. LDS 3 x 12KB = 36KB.
// ---------------------------------------------------------------------------
__global__ __launch_bounds__(256) void gemm_wo(
    const unsigned short* __restrict__ X,    // bf16 A, (MROWS x DMODEL)
    const unsigned short* __restrict__ Wob,  // bf16 Wo (1024 x 1024)
    float* __restrict__ Yf)                  // fp32 out
{
    __shared__ __align__(16) unsigned char pool[36864];
    unsigned short* base = (unsigned short*)pool;   // buf b: A at b*6144, B at +2048

    const int tid  = threadIdx.x;
    const int wave = tid >> 6;
    const int lane = tid & 63;
    const int c    = lane & 15;
    const int quad = lane >> 4;

    const int m0 = blockIdx.y * 64;
    const int n0 = blockIdx.x * 128;

    const int mhalf = (wave & 1) * 32;
    const int nhalf = (wave >> 1) * 64;

    f32x4 acc[2][4];
#pragma unroll
    for (int i = 0; i < 2; i++)
#pragma unroll
        for (int j = 0; j < 4; j++) acc[i][j] = (f32x4){0.f, 0.f, 0.f, 0.f};

    const int arow = wave * 16 + (lane >> 2);
    const int brow = wave * 32 + (lane >> 2);
    const int scol = (lane & 3) * 8;
    const unsigned short* Asrc = X   + (size_t)(m0 + arow) * DMODEL + scol;
    const unsigned short* Bsrc = Wob + (size_t)(n0 + brow) * DMODEL + scol;
    const int adoff = arow * 32 + scol;
    const int bdoff = brow * 32 + scol;

#define WO_STAGE(buf, kt) do {                                                     \
    unsigned short* _A = base + (buf) * 6144;                                      \
    unsigned short* _B = _A + 2048;                                                \
    const int _k0 = (kt) * 32;                                                     \
    gload_lds16(Asrc + _k0, _A + adoff);                                           \
    _Pragma("unroll")                                                              \
    for (int _j = 0; _j < 2; _j++)                                                 \
        gload_lds16(Bsrc + (size_t)(_j * 16) * DMODEL + _k0, _B + bdoff + _j * 512);\
} while (0)

#define WO_COMPUTE(buf) do {                                                       \
    const unsigned short* _A = base + (buf) * 6144;                                \
    const unsigned short* _B = _A + 2048;                                          \
    bf16x8 af[2], bfr[4];                                                          \
    _Pragma("unroll")                                                              \
    for (int mt = 0; mt < 2; mt++)                                                 \
        af[mt] = *(const bf16x8*)(&_A[(mhalf + mt * 16 + c) * 32 + quad * 8]);     \
    _Pragma("unroll")                                                              \
    for (int nt = 0; nt < 4; nt++)                                                 \
        bfr[nt] = *(const bf16x8*)(&_B[(nhalf + nt * 16 + c) * 32 + quad * 8]);    \
    _Pragma("unroll")                                                              \
    for (int mt = 0; mt < 2; mt++)                                                 \
        _Pragma("unroll")                                                          \
        for (int nt = 0; nt < 4; nt++)                                             \
            acc[mt][nt] = __builtin_amdgcn_mfma_f32_16x16x32_bf16(af[mt], bfr[nt], acc[mt][nt], 0, 0, 0); \
} while (0)

    WO_STAGE(0, 0);
    WO_STAGE(1, 1);
    for (int g = 0; g < 10; ++g) {
        const int t = g * 3;
        VMCNT_BAR(3); WO_STAGE(2, t + 2); WO_COMPUTE(0);
        VMCNT_BAR(3); WO_STAGE(0, t + 3); WO_COMPUTE(1);
        VMCNT_BAR(3); WO_STAGE(1, t + 4); WO_COMPUTE(2);
    }
    VMCNT_BAR(3); WO_COMPUTE(0);
    VMCNT_BAR(0); WO_COMPUTE(1);

    __syncthreads();

    float* EPf = (float*)pool + wave * 16 * 68;
    const int row = lane >> 2;
    const int cg  = lane & 3;
#pragma unroll
    for (int mt = 0; mt < 2; mt++) {
        LGKM0();
#pragma unroll
        for (int nt = 0; nt < 4; nt++)
#pragma unroll
            for (int r = 0; r < 4; r++)
                EPf[(quad * 4 + r) * 68 + nt * 16 + c] = acc[mt][nt][r];
        LGKM0();
        int m = m0 + mhalf + mt * 16 + row;
        float* dst = Yf + (size_t)m * DMODEL + n0 + nhalf + cg * 16;
#pragma unroll
        for (int j = 0; j < 4; j++)
            *(float4*)(dst + j * 4) = *(const float4*)(&EPf[row * 68 + cg * 16 + j * 4]);
    }
#undef WO_STAGE
#undef WO_COMPUTE
}

// ---------------------------------------------------------------------------
// MFMA flash attention R16: K/V double-buffered LDS, ONE barrier per K-tile,
// T14 async-split staging (issue global loads right after the barrier, LDS
// write at end of iter -> HBM latency hides under QK/softmax/PV), T5 setprio
// around both MFMA clusters (+4-7% documented on attn, m191).
// ---------------------------------------------------------------------------
__global__ __launch_bounds__(256, 4) void attn_mfma(
    const unsigned short* __restrict__ Q,
    const unsigned short* __restrict__ K,
    const unsigned short* __restrict__ Vt,
    unsigned short* __restrict__ A)
{
    __shared__ unsigned short Ks[2][32 * 72];
    __shared__ unsigned short Vs[2][64 * 40];
    __shared__ unsigned short Plds[4][16 * 40];

    const int tid  = threadIdx.x;
    const int wave = tid >> 6;
    const int lane = tid & 63;
    const int c    = lane & 15;
    const int quad = lane >> 4;

    const int bh = blockIdx.x;
    const int b  = bh >> 4;
    const int h  = bh & 15;
    const int qb = (int)(gridDim.y - 1) - (int)blockIdx.y;
    const int q0b = qb * 64;
    const int q0 = q0b + wave * 16;

    const unsigned short* Qb = Q  + (size_t)bh * S_LEN * DKH;
    const unsigned short* Kb = K  + (size_t)bh * S_LEN * DKH;
    const unsigned short* Vb = Vt + (size_t)bh * DKH * S_LEN;

    bf16x8 qf0 = *(const bf16x8*)(Qb + (q0 + c) * DKH + quad * 8);
    bf16x8 qf1 = *(const bf16x8*)(Qb + (q0 + c) * DKH + 32 + quad * 8);

    f32x4 o0 = {0.f,0.f,0.f,0.f}, o1 = o0, o2 = o0, o3 = o0;
    float l[4] = {0.f, 0.f, 0.f, 0.f};

    unsigned short* Pw = &Plds[wave][0];

    const int my_nkb   = (q0 + 16 + 31) >> 5;
    const int nkb_blk  = (q0b + 64 + 31) >> 5;
    const int kb_full  = (q0 >= 31) ? (((q0 - 31) >> 5) + 1) : 0;

    const int krow  = tid >> 3;
    const int kcol8 = (tid & 7) * 8;
    const int vrow  = tid >> 2;
    const int vcol8 = (tid & 3) * 8;

    // Prologue: tile 0 staged into buf 0.
    uint4 gK = *(const uint4*)(Kb + (size_t)krow * DKH + kcol8);
    uint4 gV = *(const uint4*)(Vb + (size_t)vrow * S_LEN + vcol8);
    *(uint4*)(&Ks[0][krow * 72 + kcol8]) = gK;
    *(uint4*)(&Vs[0][vrow * 40 + vcol8]) = gV;

    for (int kb = 0; kb < nkb_blk; kb++) {
        const int k0 = kb * 32;
        const int nb = kb + 1;
        const bool pre = nb < nkb_blk;
        __syncthreads();   // buf[kb&1] visible; buf[nb&1] reads (iter kb-1) done
        if (pre) {         // T14: issue loads now, write LDS at end of iter
            gK = *(const uint4*)(Kb + (size_t)(nb * 32 + krow) * DKH + kcol8);
            gV = *(const uint4*)(Vb + (size_t)vrow * S_LEN + nb * 32 + vcol8);
        }
        if (kb < my_nkb) {
            const unsigned short* Kc = &Ks[kb & 1][0];
            const unsigned short* Vc = &Vs[kb & 1][0];
            bf16x8 k00 = *(const bf16x8*)(&Kc[c * 72 + quad * 8]);
            bf16x8 k01 = *(const bf16x8*)(&Kc[c * 72 + 32 + quad * 8]);
            bf16x8 k10 = *(const bf16x8*)(&Kc[(16 + c) * 72 + quad * 8]);
            bf16x8 k11 = *(const bf16x8*)(&Kc[(16 + c) * 72 + 32 + quad * 8]);
            f32x4 s0 = {0.f,0.f,0.f,0.f}, s1 = {0.f,0.f,0.f,0.f};
            __builtin_amdgcn_s_setprio(1);
            s0 = __builtin_amdgcn_mfma_f32_16x16x32_bf16(qf0, k00, s0, 0, 0, 0);
            s0 = __builtin_amdgcn_mfma_f32_16x16x32_bf16(qf1, k01, s0, 0, 0, 0);
            s1 = __builtin_amdgcn_mfma_f32_16x16x32_bf16(qf0, k10, s1, 0, 0, 0);
            s1 = __builtin_amdgcn_mfma_f32_16x16x32_bf16(qf1, k11, s1, 0, 0, 0);
            __builtin_amdgcn_s_setprio(0);

            if (kb < kb_full) {
#pragma unroll
                for (int r = 0; r < 4; r++) {
                    float e0 = __expf(s0[r] * 0.125f);
                    float e1 = __expf(s1[r] * 0.125f);
                    unsigned short pb0 = f2bfu(e0);
                    unsigned short pb1 = f2bfu(e1);
                    Pw[(quad * 4 + r) * 40 + c]      = pb0;
                    Pw[(quad * 4 + r) * 40 + 16 + c] = pb1;
                    l[r] += bfu2f(pb0) + bfu2f(pb1);
                }
            } else {
#pragma unroll
                for (int r = 0; r < 4; r++) {
                    int qrow = q0 + quad * 4 + r;
                    float e0 = (k0 + c      <= qrow) ? __expf(s0[r] * 0.125f) : 0.0f;
                    float e1 = (k0 + 16 + c <= qrow) ? __expf(s1[r] * 0.125f) : 0.0f;
                    unsigned short pb0 = f2bfu(e0);
                    unsigned short pb1 = f2bfu(e1);
                    Pw[(quad * 4 + r) * 40 + c]      = pb0;
                    Pw[(quad * 4 + r) * 40 + 16 + c] = pb1;
                    l[r] += bfu2f(pb0) + bfu2f(pb1);
                }
            }
            LGKM0();

            bf16x8 pf = *(const bf16x8*)(Pw + c * 40 + quad * 8);

            bf16x8 vf0 = *(const bf16x8*)(&Vc[(0 * 16 + c) * 40 + quad * 8]);
            bf16x8 vf1 = *(const bf16x8*)(&Vc[(1 * 16 + c) * 40 + quad * 8]);
            bf16x8 vf2 = *(const bf16x8*)(&Vc[(2 * 16 + c) * 40 + quad * 8]);
            bf16x8 vf3 = *(const bf16x8*)(&Vc[(3 * 16 + c) * 40 + quad * 8]);
            __builtin_amdgcn_s_setprio(1);
            o0 = __builtin_amdgcn_mfma_f32_16x16x32_bf16(pf, vf0, o0, 0, 0, 0);
            o1 = __builtin_amdgcn_mfma_f32_16x16x32_bf16(pf, vf1, o1, 0, 0, 0);
            o2 = __builtin_amdgcn_mfma_f32_16x16x32_bf16(pf, vf2, o2, 0, 0, 0);
            o3 = __builtin_amdgcn_mfma_f32_16x16x32_bf16(pf, vf3, o3, 0, 0, 0);
            __builtin_amdgcn_s_setprio(0);
        }
        if (pre) {   // LDS write after compute: vmcnt wait paid AFTER overlap
            *(uint4*)(&Ks[nb & 1][krow * 72 + kcol8]) = gK;
            *(uint4*)(&Vs[nb & 1][vrow * 40 + vcol8]) = gV;
        }
    }

#pragma unroll
    for (int m = 1; m < 16; m <<= 1) {
#pragma unroll
        for (int r = 0; r < 4; r++) l[r] += __shfl_xor(l[r], m, 64);
    }

#pragma unroll
    for (int r = 0; r < 4; r++) {
        float inv = 1.0f / l[r];
        int s = q0 + quad * 4 + r;
        unsigned short* Ap = A + ((size_t)b * S_LEN + s) * DMODEL + h * DKH;
        Ap[0 * 16 + c] = f2bfu(o0[r] * inv);
        Ap[1 * 16 + c] = f2bfu(o1[r] * inv);
        Ap[2 * 16 + c] = f2bfu(o2[r] * inv);
        Ap[3 * 16 + c] = f2bfu(o3[r] * inv);
    }
}

extern "C" void kernel_launch(void* const* d_in, const int* in_sizes, int n_in,
                              void* d_out, int out_size, void* d_ws, size_t ws_size,
                              hipStream_t stream) {
    const float* x  = (const float*)d_in[0];
    const float* Wq = (const float*)d_in[1];
    const float* Wk = (const float*)d_in[2];
    const float* Wv = (const float*)d_in[3];
    const float* Wo = (const float*)d_in[4];
    float* out = (float*)d_out;

    // Workspace (exactly 32 MiB):
    //  [0,8)   phase A: Q bf16;  phase C: Wob bf16 (cvt_wo -> gemm_wo)
    //  [8,16)  K bf16
    //  [16,24) V^T bf16
    //  [24,32) phase A: Wqkv bf16; phase B: A (attn -> gemm_wo)
    // d_out doubles as scratch: first 8 MB holds Xb bf16 until gemm_qkv done.
    unsigned short* Qw = (unsigned short*)d_ws;
    unsigned short* Kw = Qw + (size_t)MROWS * DMODEL;
    unsigned short* Vw = Kw + (size_t)MROWS * DMODEL;
    unsigned short* Wb = Vw + (size_t)MROWS * DMODEL;
    unsigned short* Aw = Wb;    // aliased; QKV completes before attn writes A
    unsigned short* Wob = Qw;   // aliased; Q dead after attn_mfma
    unsigned short* Xb = (unsigned short*)d_out;   // scratch in output buffer

    cvt_all<<<dim3(DMODEL * DMODEL / (256 * 8), 7), 256, 0, stream>>>(Wq, Wk, Wv, x, Wb, Xb);

    gemm_qkv<<<dim3(3 * DMODEL / 128, MROWS / 128), 256, 0, stream>>>(
        Xb, Wb, Qw, Kw, Vw);

    attn_mfma<<<dim3(NHEADS * BATCH, S_LEN / 64), 256, 0, stream>>>(Qw, Kw, Vw, Aw);

    cvt_wo<<<dim3(DMODEL * DMODEL / (256 * 8)), 256, 0, stream>>>(Wo, Wob);

    gemm_wo<<<dim3(DMODEL / 128, MROWS / 64), 256, 0, stream>>>(Aw, Wob, out);
}